// Round 1
// baseline (134.728 us; speedup 1.0000x reference)
//
#include <hip/hip_runtime.h>

#define BATCH 16
#define CHN 3
#define H 512
#define W 512
#define BH 128
#define BW 128
#define HG 510   // interior rows, pixel coords 1..510 -> buffer rows 0..509
#define WG 510

// ---------------- Kernel 1: per-pixel gradient + orientation ----------------
__global__ __launch_bounds__(256) void hog_grad(const float* __restrict__ img,
                                                float* __restrict__ mag,
                                                unsigned char* __restrict__ obuf)
{
    int x = blockIdx.x * 64 + threadIdx.x;   // buffer col 0..509
    int y = blockIdx.y * 4 + threadIdx.y;    // buffer row 0..509
    int b = blockIdx.z;
    if (x >= WG || y >= HG) return;
    int py = y + 1, px = x + 1;              // pixel coords

    const float* im = img + (size_t)b * CHN * H * W;
    float bestv = -1.0f, bdx = 0.0f, bdy = 0.0f;
#pragma unroll
    for (int c = 0; c < CHN; c++) {
        const float* p = im + (size_t)c * H * W;
        float dyv = __fsub_rn(p[(size_t)(py + 1) * W + px], p[(size_t)(py - 1) * W + px]);
        float dxv = __fsub_rn(p[(size_t)py * W + px + 1], p[(size_t)py * W + px - 1]);
        // no FMA contraction: match numpy rounding exactly (argmax is discontinuous)
        float v = __fadd_rn(__fmul_rn(dxv, dxv), __fmul_rn(dyv, dyv));
        if (v > bestv) { bestv = v; bdx = dxv; bdy = dyv; }
    }
    float mg = __fsqrt_rn(bestv);  // identical value to sqrt(dx*dx+dy*dy)

    const float uu[9] = {1.0f, 0.9397f, 0.766f, 0.5f, 0.1736f, -0.1736f, -0.5f, -0.766f, -0.9397f};
    const float vvt[9] = {0.0f, 0.342f, 0.6428f, 0.866f, 0.9848f, 0.9848f, 0.866f, 0.6428f, 0.342f};
    float d[9];
#pragma unroll
    for (int o = 0; o < 9; o++)
        d[o] = __fadd_rn(__fmul_rn(uu[o], bdx), __fmul_rn(vvt[o], bdy));
    float best = -1e30f; int bo = 0;
#pragma unroll
    for (int o = 0; o < 9; o++) { if (d[o] > best) { best = d[o]; bo = o; } }
#pragma unroll
    for (int o = 0; o < 9; o++) { float nd = -d[o]; if (nd > best) { best = nd; bo = o + 9; } }

    size_t idx = ((size_t)b * HG + y) * WG + x;
    mag[idx] = mg;
    obuf[idx] = (unsigned char)bo;
}

// ---------------- Kernel 2: per-cell 8x8 bilinear gather -> hist + norm ----------------
__global__ __launch_bounds__(256) void hog_hist(const float* __restrict__ mag,
                                                const unsigned char* __restrict__ obuf,
                                                float* __restrict__ hist,
                                                float* __restrict__ nrm)
{
    __shared__ float hl[18 * 256];
    int cx = threadIdx.x;                         // 0..127
    int cy = blockIdx.y * 2 + threadIdx.y;        // 0..127
    int b = blockIdx.z;
    int t = threadIdx.y * 128 + cx;               // 0..255

#pragma unroll
    for (int o = 0; o < 18; o++) hl[o * 256 + t] = 0.0f;
    // private per-thread hist columns -> no barrier needed

    const float wt[8] = {0.125f, 0.375f, 0.625f, 0.875f, 0.875f, 0.625f, 0.375f, 0.125f};
    const float* mb = mag + (size_t)b * HG * WG;
    const unsigned char* ob = obuf + (size_t)b * HG * WG;
    int ry0 = 4 * cy - 3;   // buffer row of ky=0
    int rx0 = 4 * cx - 3;   // buffer col of kx=0

#pragma unroll
    for (int ky = 0; ky < 8; ky++) {
        int ry = ry0 + ky;
        if ((unsigned)ry >= (unsigned)HG) continue;
        float wy = wt[ky];
        const float* mr = mb + (size_t)ry * WG;
        const unsigned char* orr = ob + (size_t)ry * WG;
#pragma unroll
        for (int kx = 0; kx < 8; kx++) {
            int rx = rx0 + kx;
            if ((unsigned)rx >= (unsigned)WG) continue;
            float m = mr[rx];
            int o = orr[rx];
            hl[o * 256 + t] += (wy * wt[kx]) * m;   // weight product exact in binary
        }
    }

    float h[18];
#pragma unroll
    for (int o = 0; o < 18; o++) {
        h[o] = hl[o * 256 + t];
        hist[(((size_t)b * 18 + o) * BH + cy) * BW + cx] = h[o];
    }
    float s = 0.0f;
#pragma unroll
    for (int o = 0; o < 9; o++) { float ss = h[o] + h[o + 9]; s += ss * ss; }
    nrm[((size_t)b * BH + cy) * BW + cx] = s;
}

// ---------------- Kernel 3: normalization + features + zero border ----------------
__global__ __launch_bounds__(256) void hog_feat(const float* __restrict__ hist,
                                                const float* __restrict__ nrm,
                                                float* __restrict__ out)
{
    int ox = threadIdx.x;                         // 0..127
    int oy = blockIdx.y * 2 + threadIdx.y;        // 0..127
    int b = blockIdx.z;

    if (ox == 0 || ox == BW - 1 || oy == 0 || oy == BH - 1) {
#pragma unroll
        for (int c = 0; c < 31; c++)
            out[(((size_t)b * 31 + c) * BH + oy) * BW + ox] = 0.0f;
        return;
    }

    const float* nb = nrm + (size_t)b * BH * BW;
    float n00 = nb[(size_t)(oy - 1) * BW + ox - 1], n01 = nb[(size_t)(oy - 1) * BW + ox], n02 = nb[(size_t)(oy - 1) * BW + ox + 1];
    float n10 = nb[(size_t)oy * BW + ox - 1],       n11 = nb[(size_t)oy * BW + ox],       n12 = nb[(size_t)oy * BW + ox + 1];
    float n20 = nb[(size_t)(oy + 1) * BW + ox - 1], n21 = nb[(size_t)(oy + 1) * BW + ox], n22 = nb[(size_t)(oy + 1) * BW + ox + 1];

    float T11 = n11 + n21 + n12 + n22;  // T[oy  , ox  ]  -> n1
    float T01 = n01 + n11 + n02 + n12;  // T[oy-1, ox  ]  -> n2
    float T10 = n10 + n20 + n11 + n21;  // T[oy  , ox-1]  -> n3
    float T00 = n00 + n10 + n01 + n11;  // T[oy-1, ox-1]  -> n4
    float v1 = 1.0f / __fsqrt_rn(T11 + 1e-4f);
    float v2 = 1.0f / __fsqrt_rn(T01 + 1e-4f);
    float v3 = 1.0f / __fsqrt_rn(T10 + 1e-4f);
    float v4 = 1.0f / __fsqrt_rn(T00 + 1e-4f);

    float h[18];
#pragma unroll
    for (int o = 0; o < 18; o++)
        h[o] = hist[(((size_t)b * 18 + o) * BH + oy) * BW + ox];

    float t1 = 0.f, t2 = 0.f, t3 = 0.f, t4 = 0.f;
#pragma unroll
    for (int o = 0; o < 18; o++) {
        float s = h[o];
        float a1 = fminf(s * v1, 0.2f);
        float a2 = fminf(s * v2, 0.2f);
        float a3 = fminf(s * v3, 0.2f);
        float a4 = fminf(s * v4, 0.2f);
        out[(((size_t)b * 31 + o) * BH + oy) * BW + ox] = 0.5f * (a1 + a2 + a3 + a4);
        t1 += a1; t2 += a2; t3 += a3; t4 += a4;
    }
#pragma unroll
    for (int o = 0; o < 9; o++) {
        float ss = h[o] + h[o + 9];
        float a1 = fminf(ss * v1, 0.2f);
        float a2 = fminf(ss * v2, 0.2f);
        float a3 = fminf(ss * v3, 0.2f);
        float a4 = fminf(ss * v4, 0.2f);
        out[(((size_t)b * 31 + 18 + o) * BH + oy) * BW + ox] = 0.5f * (a1 + a2 + a3 + a4);
    }
    out[(((size_t)b * 31 + 27) * BH + oy) * BW + ox] = 0.2357f * t1;
    out[(((size_t)b * 31 + 28) * BH + oy) * BW + ox] = 0.2357f * t2;
    out[(((size_t)b * 31 + 29) * BH + oy) * BW + ox] = 0.2357f * t3;
    out[(((size_t)b * 31 + 30) * BH + oy) * BW + ox] = 0.2357f * t4;
}

extern "C" void kernel_launch(void* const* d_in, const int* in_sizes, int n_in,
                              void* d_out, int out_size, void* d_ws, size_t ws_size,
                              hipStream_t stream)
{
    const float* img = (const float*)d_in[0];
    float* out = (float*)d_out;
    char* ws = (char*)d_ws;

    // workspace layout (bytes):
    //   mag  : 16*510*510*4 = 16,646,400
    //   obuf : 16*510*510   =  4,161,600   (ends 20,808,000)
    //   hist : 16*18*128*128*4 = 18,874,368 (ends 39,682,368)
    //   nrm  : 16*128*128*4 = 1,048,576    (total 40,730,944)
    float* mag          = (float*)ws;
    unsigned char* obuf = (unsigned char*)(ws + 16646400);
    float* hist         = (float*)(ws + 20808000);
    float* nrm          = (float*)(ws + 39682368);

    dim3 b1(64, 4, 1), g1((WG + 63) / 64, (HG + 3) / 4, BATCH);
    hog_grad<<<g1, b1, 0, stream>>>(img, mag, obuf);

    dim3 b2(128, 2, 1), g2(1, BH / 2, BATCH);
    hog_hist<<<g2, b2, 0, stream>>>(mag, obuf, hist, nrm);
    hog_feat<<<g2, b2, 0, stream>>>(hist, nrm, out);
}

// Round 2
// 120.478 us; speedup vs baseline: 1.1183x; 1.1183x over previous
//
#include <hip/hip_runtime.h>

#define BATCH 16
#define H 512
#define W 512
#define BH 128
#define BW 128
#define HG 510   // interior rows (buffer rows 0..509 <-> pixel rows 1..510)
#define WG 510
#define PKW 512  // padded row stride of packed intermediate

// pack: (mag_bits & ~31) | o   -- o in [0,18) fits 5 bits; mag rel err ~3e-6
// o is chosen BEFORE truncation, so argmax decisions are bit-identical to ref.

// ---------------- Kernel 1: gradient + orientation, 4 px/thread ----------------
__global__ __launch_bounds__(256) void hog_grad(const float* __restrict__ img,
                                                unsigned int* __restrict__ pk)
{
    int tx = threadIdx.x;
    int gx = blockIdx.x * 64 + tx;          // quad index 0..127
    int y  = blockIdx.y * 4 + threadIdx.y;  // buffer row
    int b  = blockIdx.z;
    if (y >= HG) return;
    int x0 = gx * 4;                        // buffer col of px 0 (0..508)
    bool tail = (x0 == 508);                // last quad: window shifts left by 4
    int w0 = tail ? 504 : x0;
    int py = y + 1;

    const float* im = img + (size_t)b * 3 * H * W;

    float bv0 = -1.f, bv1 = -1.f, bv2 = -1.f, bv3 = -1.f;
    float bx0 = 0, bx1 = 0, bx2 = 0, bx3 = 0;
    float by0 = 0, by1 = 0, by2 = 0, by3 = 0;

#pragma unroll
    for (int c = 0; c < 3; c++) {
        const float* base = im + (size_t)c * H * W;
        const float* rm = base + (size_t)(py - 1) * W + w0;
        const float* rc = base + (size_t)py * W + w0;
        const float* rp = base + (size_t)(py + 1) * W + w0;
        float4 ma = *(const float4*)rm, mb = *(const float4*)(rm + 4);
        float4 ca = *(const float4*)rc, cb = *(const float4*)(rc + 4);
        float4 pa = *(const float4*)rp, pb = *(const float4*)(rp + 4);
        // shifted window W[off+k]; off=0 normal, off=4 tail (clamped idx>7 -> 7,
        // only reaches lanes/pixels that are masked out at store time)
        float M1 = tail ? mb.y : ma.y, M2 = tail ? mb.z : ma.z;
        float M3 = tail ? mb.w : ma.w, M4 = tail ? mb.w : mb.x;
        float P1 = tail ? pb.y : pa.y, P2 = tail ? pb.z : pa.z;
        float P3 = tail ? pb.w : pa.w, P4 = tail ? pb.w : pb.x;
        float C0 = tail ? cb.x : ca.x, C1 = tail ? cb.y : ca.y;
        float C2 = tail ? cb.z : ca.z, C3 = tail ? cb.w : ca.w;
        float C4 = tail ? cb.w : cb.x, C5 = tail ? cb.w : cb.y;

        float dx0 = __fsub_rn(C2, C0), dx1 = __fsub_rn(C3, C1);
        float dx2 = __fsub_rn(C4, C2), dx3 = __fsub_rn(C5, C3);
        float dy0 = __fsub_rn(P1, M1), dy1 = __fsub_rn(P2, M2);
        float dy2 = __fsub_rn(P3, M3), dy3 = __fsub_rn(P4, M4);

        float v0 = __fadd_rn(__fmul_rn(dx0, dx0), __fmul_rn(dy0, dy0));
        float v1 = __fadd_rn(__fmul_rn(dx1, dx1), __fmul_rn(dy1, dy1));
        float v2 = __fadd_rn(__fmul_rn(dx2, dx2), __fmul_rn(dy2, dy2));
        float v3 = __fadd_rn(__fmul_rn(dx3, dx3), __fmul_rn(dy3, dy3));
        if (v0 > bv0) { bv0 = v0; bx0 = dx0; by0 = dy0; }
        if (v1 > bv1) { bv1 = v1; bx1 = dx1; by1 = dy1; }
        if (v2 > bv2) { bv2 = v2; bx2 = dx2; by2 = dy2; }
        if (v3 > bv3) { bv3 = v3; bx3 = dx3; by3 = dy3; }
    }

    const float uu[9] = {1.0f, 0.9397f, 0.766f, 0.5f, 0.1736f, -0.1736f, -0.5f, -0.766f, -0.9397f};
    const float vv[9] = {0.0f, 0.342f, 0.6428f, 0.866f, 0.9848f, 0.9848f, 0.866f, 0.6428f, 0.342f};

    unsigned int pkv[4];
    float bvv[4] = {bv0, bv1, bv2, bv3};
    float bxx[4] = {bx0, bx1, bx2, bx3};
    float byy[4] = {by0, by1, by2, by3};
#pragma unroll
    for (int i = 0; i < 4; i++) {
        float mg = __fsqrt_rn(bvv[i]);
        float best = -1e30f; int bo = 0;
#pragma unroll
        for (int o = 0; o < 9; o++) {
            float d = __fadd_rn(__fmul_rn(uu[o], bxx[i]), __fmul_rn(vv[o], byy[i]));
            if (d > best) { best = d; bo = o; }
            float nd = -d;  // second half checked after: keep order o then o+9
            (void)nd;
        }
#pragma unroll
        for (int o = 0; o < 9; o++) {
            float d = __fadd_rn(__fmul_rn(uu[o], bxx[i]), __fmul_rn(vv[o], byy[i]));
            float nd = -d;
            if (nd > best) { best = nd; bo = o + 9; }
        }
        unsigned int v = (__float_as_uint(mg) & 0xFFFFFFE0u) | (unsigned int)bo;
        pkv[i] = (x0 + i < WG) ? v : 0u;   // zero pad cols 510/511
    }
    uint4 o4 = make_uint4(pkv[0], pkv[1], pkv[2], pkv[3]);
    *(uint4*)(pk + ((size_t)b * HG + y) * PKW + x0) = o4;
}

// ---------------- Kernel 2: per-cell 8x8 bilinear gather -> hist + norm ----------------
__global__ __launch_bounds__(256) void hog_hist(const unsigned int* __restrict__ pk,
                                                float* __restrict__ hist,
                                                float* __restrict__ nrm)
{
    __shared__ float hl[18 * 256];
    int cx = threadIdx.x;                   // 0..127
    int cy = blockIdx.y * 2 + threadIdx.y;  // 0..127
    int b = blockIdx.z;
    int t = threadIdx.y * 128 + cx;

#pragma unroll
    for (int o = 0; o < 18; o++) hl[o * 256 + t] = 0.0f;
    // per-thread private columns: no barrier; bank = t%32 -> 2-way (free)

    const float wt[8] = {0.125f, 0.375f, 0.625f, 0.875f, 0.875f, 0.625f, 0.375f, 0.125f};
    const float wl[4] = {0.0f, 0.125f, 0.375f, 0.625f};   // pixels 4c-4..4c-1
    const float wm[4] = {0.875f, 0.875f, 0.625f, 0.375f}; // pixels 4c..4c+3

    const unsigned int* pb = pk + (size_t)b * HG * PKW;
    int ry0 = 4 * cy - 3;
    int xb = 4 * cx;

#pragma unroll
    for (int ky = 0; ky < 8; ky++) {
        int ry = ry0 + ky;
        if ((unsigned)ry >= (unsigned)HG) continue;  // wave-uniform
        float wy = wt[ky];
        const unsigned int* row = pb + (size_t)ry * PKW;
        if (cx > 0) {
            uint4 L = *(const uint4*)(row + xb - 4);
            { unsigned p = L.y; hl[(p & 31u) * 256 + t] += (wy * wl[1]) * __uint_as_float(p & 0xFFFFFFE0u); }
            { unsigned p = L.z; hl[(p & 31u) * 256 + t] += (wy * wl[2]) * __uint_as_float(p & 0xFFFFFFE0u); }
            { unsigned p = L.w; hl[(p & 31u) * 256 + t] += (wy * wl[3]) * __uint_as_float(p & 0xFFFFFFE0u); }
        }
        uint4 M = *(const uint4*)(row + xb);
        { unsigned p = M.x; hl[(p & 31u) * 256 + t] += (wy * wm[0]) * __uint_as_float(p & 0xFFFFFFE0u); }
        { unsigned p = M.y; hl[(p & 31u) * 256 + t] += (wy * wm[1]) * __uint_as_float(p & 0xFFFFFFE0u); }
        if (cx < 127) {
            { unsigned p = M.z; hl[(p & 31u) * 256 + t] += (wy * wm[2]) * __uint_as_float(p & 0xFFFFFFE0u); }
            { unsigned p = M.w; hl[(p & 31u) * 256 + t] += (wy * wm[3]) * __uint_as_float(p & 0xFFFFFFE0u); }
            unsigned p = row[xb + 4];
            hl[(p & 31u) * 256 + t] += (wy * 0.125f) * __uint_as_float(p & 0xFFFFFFE0u);
        }
    }

    float h[18];
#pragma unroll
    for (int o = 0; o < 18; o++) {
        h[o] = hl[o * 256 + t];
        hist[(((size_t)b * 18 + o) * BH + cy) * BW + cx] = h[o];
    }
    float s = 0.0f;
#pragma unroll
    for (int o = 0; o < 9; o++) { float ss = h[o] + h[o + 9]; s += ss * ss; }
    nrm[((size_t)b * BH + cy) * BW + cx] = s;
}

// ---------------- Kernel 3: normalization + features + zero border ----------------
__global__ __launch_bounds__(256) void hog_feat(const float* __restrict__ hist,
                                                const float* __restrict__ nrm,
                                                float* __restrict__ out)
{
    int ox = threadIdx.x;
    int oy = blockIdx.y * 2 + threadIdx.y;
    int b = blockIdx.z;

    if (ox == 0 || ox == BW - 1 || oy == 0 || oy == BH - 1) {
#pragma unroll
        for (int c = 0; c < 31; c++)
            out[(((size_t)b * 31 + c) * BH + oy) * BW + ox] = 0.0f;
        return;
    }

    const float* nb = nrm + (size_t)b * BH * BW;
    float n00 = nb[(size_t)(oy - 1) * BW + ox - 1], n01 = nb[(size_t)(oy - 1) * BW + ox], n02 = nb[(size_t)(oy - 1) * BW + ox + 1];
    float n10 = nb[(size_t)oy * BW + ox - 1],       n11 = nb[(size_t)oy * BW + ox],       n12 = nb[(size_t)oy * BW + ox + 1];
    float n20 = nb[(size_t)(oy + 1) * BW + ox - 1], n21 = nb[(size_t)(oy + 1) * BW + ox], n22 = nb[(size_t)(oy + 1) * BW + ox + 1];

    float T11 = n11 + n21 + n12 + n22;
    float T01 = n01 + n11 + n02 + n12;
    float T10 = n10 + n20 + n11 + n21;
    float T00 = n00 + n10 + n01 + n11;
    float v1 = 1.0f / __fsqrt_rn(T11 + 1e-4f);
    float v2 = 1.0f / __fsqrt_rn(T01 + 1e-4f);
    float v3 = 1.0f / __fsqrt_rn(T10 + 1e-4f);
    float v4 = 1.0f / __fsqrt_rn(T00 + 1e-4f);

    float h[18];
#pragma unroll
    for (int o = 0; o < 18; o++)
        h[o] = hist[(((size_t)b * 18 + o) * BH + oy) * BW + ox];

    float t1 = 0.f, t2 = 0.f, t3 = 0.f, t4 = 0.f;
#pragma unroll
    for (int o = 0; o < 18; o++) {
        float s = h[o];
        float a1 = fminf(s * v1, 0.2f);
        float a2 = fminf(s * v2, 0.2f);
        float a3 = fminf(s * v3, 0.2f);
        float a4 = fminf(s * v4, 0.2f);
        out[(((size_t)b * 31 + o) * BH + oy) * BW + ox] = 0.5f * (a1 + a2 + a3 + a4);
        t1 += a1; t2 += a2; t3 += a3; t4 += a4;
    }
#pragma unroll
    for (int o = 0; o < 9; o++) {
        float ss = h[o] + h[o + 9];
        float a1 = fminf(ss * v1, 0.2f);
        float a2 = fminf(ss * v2, 0.2f);
        float a3 = fminf(ss * v3, 0.2f);
        float a4 = fminf(ss * v4, 0.2f);
        out[(((size_t)b * 31 + 18 + o) * BH + oy) * BW + ox] = 0.5f * (a1 + a2 + a3 + a4);
    }
    out[(((size_t)b * 31 + 27) * BH + oy) * BW + ox] = 0.2357f * t1;
    out[(((size_t)b * 31 + 28) * BH + oy) * BW + ox] = 0.2357f * t2;
    out[(((size_t)b * 31 + 29) * BH + oy) * BW + ox] = 0.2357f * t3;
    out[(((size_t)b * 31 + 30) * BH + oy) * BW + ox] = 0.2357f * t4;
}

extern "C" void kernel_launch(void* const* d_in, const int* in_sizes, int n_in,
                              void* d_out, int out_size, void* d_ws, size_t ws_size,
                              hipStream_t stream)
{
    const float* img = (const float*)d_in[0];
    float* out = (float*)d_out;
    char* ws = (char*)d_ws;

    // workspace layout (256-aligned offsets):
    //   pk   : 16*510*512*4 = 16,711,680  @ 0
    //   hist : 16*18*128*128*4 = 18,874,368 @ 16,715,776
    //   nrm  : 16*128*128*4 = 1,048,576  @ 35,590,144   (end 36,638,720)
    unsigned int* pk = (unsigned int*)ws;
    float* hist      = (float*)(ws + 16715776);
    float* nrm       = (float*)(ws + 35590144);

    dim3 b1(64, 4, 1), g1(2, 128, BATCH);
    hog_grad<<<g1, b1, 0, stream>>>(img, pk);

    dim3 b2(128, 2, 1), g2(1, BH / 2, BATCH);
    hog_hist<<<g2, b2, 0, stream>>>(pk, hist, nrm);
    hog_feat<<<g2, b2, 0, stream>>>(hist, nrm, out);
}